// Round 9
// baseline (429.861 us; speedup 1.0000x reference)
//
#include <hip/hip_runtime.h>
#include <hip/hip_bf16.h>

typedef __bf16 bf16_t;
typedef __bf16 bf16x8 __attribute__((ext_vector_type(8)));
typedef __bf16 bf16x4 __attribute__((ext_vector_type(4)));
typedef float f32x4 __attribute__((ext_vector_type(4)));

#define QS   256.0f
#define QINV 0.00390625f

__device__ __forceinline__ void async_copy16(const bf16_t* g, bf16_t* l) {
  __builtin_amdgcn_global_load_lds(
      (__attribute__((address_space(1))) void*)g,
      (__attribute__((address_space(3))) void*)l,
      16, 0, 0);
}

__device__ __forceinline__ float gelu_quant(float c, float ytA, float ytS) {
  float xq = rintf(c * QS) * QINV;           // float2fix (Positional_0)
  float t = (xq + 4.0f) * 4.0f;              // exact: /0.25
  int ii = (int)t;
  ii = ii < 0 ? 0 : (ii > 31 ? 31 : ii);
  float f = t - (float)ii;
  float y0 = __shfl(ytA, ii);
  float sl = __shfl(ytS, ii);
  float v = fmaf(f, sl, y0);
  v = (xq > 4.0f) ? xq : v;
  v = (xq < -4.0f) ? 0.0f : v;
  return rintf(v * QS) * QINV;               // quantize out
}

// ======================= GEMM1: verified round-0 128^2 kernel ==============
// C = quantize-epilogue(A @ Bt^T + bias); 16x16x32 MFMA, wave = 64x64.
// LDS XOR swizzle via pre-permuted global chunk; conflict-free; 881 TF.
template <bool GELU, typename OutT>
__global__ __launch_bounds__(256, 4)
void gemm128(const bf16_t* __restrict__ A, const bf16_t* __restrict__ Bt,
             const float* __restrict__ bias, OutT* __restrict__ C,
             int M, int N, int K) {
  __shared__ __attribute__((aligned(16))) bf16_t As[128 * 64];
  __shared__ __attribute__((aligned(16))) bf16_t Bs[128 * 64];

  const int tid = threadIdx.x;
  const int lane = tid & 63;
  const int wv = tid >> 6;
  const int wy = wv >> 1;
  const int wx = wv & 1;
  const int l15 = lane & 15;
  const int lq = lane >> 4;

  float ytA = 0.f, ytS = 0.f;
  if (GELU) {
    float xv = -4.0f + 0.25f * (float)lane;
    float y0 = 0.5f * xv * (1.0f + erff(xv * 0.70710678f));
    float xv1 = xv + 0.25f;
    float y1 = 0.5f * xv1 * (1.0f + erff(xv1 * 0.70710678f));
    ytA = y0;
    ytS = y1 - y0;
  }

  const int mBase = blockIdx.y * 128;
  const int nBase = blockIdx.x * 128;
  const bf16_t* aTile = A + (size_t)mBase * K;
  const bf16_t* bTile = Bt + (size_t)nBase * K;

  f32x4 acc[4][4];
#pragma unroll
  for (int i = 0; i < 4; ++i)
#pragma unroll
    for (int j = 0; j < 4; ++j)
      acc[i][j] = (f32x4){0.f, 0.f, 0.f, 0.f};

  const int srow = tid >> 3;
  const int scb = (((tid & 7) ^ ((tid >> 3) & 7)) * 8);
  const int swz_r = l15 & 7;

  for (int k0 = 0; k0 < K; k0 += 64) {
#pragma unroll
    for (int p = 0; p < 4; ++p) {
      const int row = p * 32 + srow;
      const size_t go = (size_t)row * K + k0 + scb;
      const int lo = (p * 256 + wv * 64) * 8;
      async_copy16(aTile + go, As + lo);
      async_copy16(bTile + go, Bs + lo);
    }
    __syncthreads();

#pragma unroll
    for (int ks = 0; ks < 2; ++ks) {
      const int swzA = ((ks * 4 + lq) ^ swz_r) * 8;
      bf16x8 af[4], bfr[4];
#pragma unroll
      for (int i = 0; i < 4; ++i) {
        af[i]  = *(const bf16x8*)(As + (wy * 64 + i * 16 + l15) * 64 + swzA);
        bfr[i] = *(const bf16x8*)(Bs + (wx * 64 + i * 16 + l15) * 64 + swzA);
      }
#pragma unroll
      for (int i = 0; i < 4; ++i)
#pragma unroll
        for (int j = 0; j < 4; ++j)
          acc[i][j] = __builtin_amdgcn_mfma_f32_16x16x32_bf16(af[i], bfr[j], acc[i][j], 0, 0, 0);
    }
    __syncthreads();
  }

  float bj[4];
#pragma unroll
  for (int j = 0; j < 4; ++j)
    bj[j] = bias[nBase + wx * 64 + j * 16 + l15];

#pragma unroll
  for (int i = 0; i < 4; ++i) {
    const int rb = mBase + wy * 64 + i * 16 + lq * 4;
#pragma unroll
    for (int j = 0; j < 4; ++j) {
      const int cn = nBase + wx * 64 + j * 16 + l15;
#pragma unroll
      for (int r = 0; r < 4; ++r) {
        float c = acc[i][j][r] + bj[j];
        float v = GELU ? gelu_quant(c, ytA, ytS) : rintf(c * QS) * QINV;
        C[(size_t)(rb + r) * N + cn] = (OutT)v;
      }
    }
  }
}

// ======================= GEMM2: 256^2 8-phase, NO sched_barrier ============
// r3's verified schedule with the m141 variable removed: no sched_barrier(0)
// anywhere -- compiler keeps freedom to interleave ds_read/MFMA/stage within
// each phase (its dataflow-counted lgkmcnt protects MFMA operands).
template <int SHIFT>
__device__ __forceinline__ void stage_unit(const bf16_t* __restrict__ gk, bf16_t* lbuf,
                                           int K, int halfOff, int tid) {
  const int scb = (((tid & 7) ^ ((tid >> 3) & 7)) << 3);
  const int MASK = (1 << SHIFT) - 1;
#pragma unroll
  for (int q = 0; q < 2; ++q) {
    const int u  = q * 64 + (tid >> 3);
    const int u0 = q * 64 + ((tid >> 6) << 3);
    const int row  = halfOff + (u  & MASK) + ((u  >> SHIFT) << (SHIFT + 1));
    const int row0 = halfOff + (u0 & MASK) + ((u0 >> SHIFT) << (SHIFT + 1));
    async_copy16(gk + (size_t)row * K + scb, lbuf + row0 * 64);
  }
}

__device__ __forceinline__ bf16x8 ldfrag(const bf16_t* buf, int row, int ks, int lq) {
  const int phys = ((ks << 2) | lq) ^ (row & 7);
  return *(const bf16x8*)(buf + row * 64 + (phys << 3));
}

__device__ __forceinline__ void ktile(
    const bf16_t* __restrict__ Ab, const bf16_t* __restrict__ Bb,
    bf16_t* __restrict__ An, bf16_t* __restrict__ Bn,
    const bf16_t* __restrict__ aN, const bf16_t* __restrict__ bN,
    const bool nl, const int tid, const int rA0, const int rB0, const int lq,
    const int K, f32x4 (&acc)[8][4]) {
  bf16x8 fa[2][4];
  bf16x8 fb[2][2][2];

  // -------- P0: reads U0+U1; MFMA Q00; stages next U0
#pragma unroll
  for (int ks = 0; ks < 2; ++ks) {
#pragma unroll
    for (int i = 0; i < 4; ++i) fa[ks][i] = ldfrag(Ab, rA0 + i * 16, ks, lq);
#pragma unroll
    for (int j = 0; j < 2; ++j) fb[0][ks][j] = ldfrag(Bb, rB0 + j * 16, ks, lq);
  }
  if (nl) {
    stage_unit<6>(aN, An, K, 0, tid);
    asm volatile("s_waitcnt vmcnt(4)" ::: "memory");  // drains this tile's U2
  } else {
    asm volatile("s_waitcnt vmcnt(2)" ::: "memory");
  }
  __builtin_amdgcn_s_barrier();
  asm volatile("s_waitcnt lgkmcnt(0)" ::: "memory");
  __builtin_amdgcn_s_setprio(1);
#pragma unroll
  for (int ks = 0; ks < 2; ++ks)
#pragma unroll
    for (int i = 0; i < 4; ++i)
#pragma unroll
      for (int j = 0; j < 2; ++j)
        acc[i][j] = __builtin_amdgcn_mfma_f32_16x16x32_bf16(fa[ks][i], fb[0][ks][j], acc[i][j], 0, 0, 0);
  __builtin_amdgcn_s_setprio(0);
  __builtin_amdgcn_s_barrier();

  // -------- P1: reads U2 (fb1); MFMA Q01; stages next U1
#pragma unroll
  for (int ks = 0; ks < 2; ++ks)
#pragma unroll
    for (int j = 0; j < 2; ++j) fb[1][ks][j] = ldfrag(Bb, rB0 + 32 + j * 16, ks, lq);
  if (nl) {
    stage_unit<5>(bN, Bn, K, 0, tid);
    asm volatile("s_waitcnt vmcnt(4)" ::: "memory");  // drains this tile's U3
  } else {
    asm volatile("s_waitcnt vmcnt(0)" ::: "memory");
  }
  __builtin_amdgcn_s_barrier();
  asm volatile("s_waitcnt lgkmcnt(0)" ::: "memory");
  __builtin_amdgcn_s_setprio(1);
#pragma unroll
  for (int ks = 0; ks < 2; ++ks)
#pragma unroll
    for (int i = 0; i < 4; ++i)
#pragma unroll
      for (int j = 0; j < 2; ++j)
        acc[i][2 + j] = __builtin_amdgcn_mfma_f32_16x16x32_bf16(fa[ks][i], fb[1][ks][j], acc[i][2 + j], 0, 0, 0);
  __builtin_amdgcn_s_setprio(0);
  __builtin_amdgcn_s_barrier();

  // -------- P2: reads U3 (fa half1); MFMA Q11; stages next U2
#pragma unroll
  for (int ks = 0; ks < 2; ++ks)
#pragma unroll
    for (int i = 0; i < 4; ++i) fa[ks][i] = ldfrag(Ab, rA0 + 64 + i * 16, ks, lq);
  if (nl) stage_unit<5>(bN, Bn, K, 32, tid);
  __builtin_amdgcn_s_barrier();
  asm volatile("s_waitcnt lgkmcnt(0)" ::: "memory");
  __builtin_amdgcn_s_setprio(1);
#pragma unroll
  for (int ks = 0; ks < 2; ++ks)
#pragma unroll
    for (int i = 0; i < 4; ++i)
#pragma unroll
      for (int j = 0; j < 2; ++j)
        acc[4 + i][2 + j] = __builtin_amdgcn_mfma_f32_16x16x32_bf16(fa[ks][i], fb[1][ks][j], acc[4 + i][2 + j], 0, 0, 0);
  __builtin_amdgcn_s_setprio(0);
  __builtin_amdgcn_s_barrier();

  // -------- P3: MFMA Q10; stages next U3
  if (nl) {
    stage_unit<6>(aN, An, K, 64, tid);
    asm volatile("s_waitcnt vmcnt(4)" ::: "memory");  // drains next tile's U0,U1
  }
  __builtin_amdgcn_s_barrier();
  __builtin_amdgcn_s_setprio(1);
#pragma unroll
  for (int ks = 0; ks < 2; ++ks)
#pragma unroll
    for (int i = 0; i < 4; ++i)
#pragma unroll
      for (int j = 0; j < 2; ++j)
        acc[4 + i][j] = __builtin_amdgcn_mfma_f32_16x16x32_bf16(fa[ks][i], fb[0][ks][j], acc[4 + i][j], 0, 0, 0);
  __builtin_amdgcn_s_setprio(0);
  __builtin_amdgcn_s_barrier();
}

template <bool GELU, typename OutT>
__global__ __launch_bounds__(512, 2)
void gemm256(const bf16_t* __restrict__ A, const bf16_t* __restrict__ Bt,
             const float* __restrict__ bias, OutT* __restrict__ C,
             int M, int N, int K) {
  __shared__ __attribute__((aligned(16))) bf16_t As0[256 * 64];
  __shared__ __attribute__((aligned(16))) bf16_t Bs0[256 * 64];
  __shared__ __attribute__((aligned(16))) bf16_t As1[256 * 64];
  __shared__ __attribute__((aligned(16))) bf16_t Bs1[256 * 64];

  const int tid = threadIdx.x;
  const int lane = tid & 63;
  const int wid = tid >> 6;
  const int wr = wid >> 2;
  const int wc = wid & 3;
  const int l15 = lane & 15;
  const int lq = lane >> 4;

  float ytA = 0.f, ytS = 0.f;
  if (GELU) {
    float xv = -4.0f + 0.25f * (float)lane;
    float y0 = 0.5f * xv * (1.0f + erff(xv * 0.70710678f));
    float xv1 = xv + 0.25f;
    float y1 = 0.5f * xv1 * (1.0f + erff(xv1 * 0.70710678f));
    ytA = y0;
    ytS = y1 - y0;
  }

  // NO swizzle: default round-robin gives XCD k a fixed N-column (bx = k&3
  // for gridDim.x=4) -> 2MB B-panel slice per L2, A rows shared via L3.
  const int mBase = blockIdx.y * 256;
  const int nBase = blockIdx.x * 256;
  const bf16_t* aTile = A + (size_t)mBase * K;
  const bf16_t* bTile = Bt + (size_t)nBase * K;

  f32x4 acc[8][4];
#pragma unroll
  for (int i = 0; i < 8; ++i)
#pragma unroll
    for (int j = 0; j < 4; ++j)
      acc[i][j] = (f32x4){0.f, 0.f, 0.f, 0.f};

  const int nT = K >> 6;  // 64 for GEMM2: even
  const int rA0 = wr * 128 + l15;
  const int rB0 = wc * 64 + l15;

  stage_unit<6>(aTile, As0, K, 0, tid);
  stage_unit<5>(bTile, Bs0, K, 0, tid);
  stage_unit<5>(bTile, Bs0, K, 32, tid);
  stage_unit<6>(aTile, As0, K, 64, tid);
  asm volatile("s_waitcnt vmcnt(4)" ::: "memory");
  __builtin_amdgcn_s_barrier();

  for (int tt = 0; tt < nT; tt += 2) {
    ktile(As0, Bs0, As1, Bs1,
          aTile + (size_t)(tt + 1) * 64, bTile + (size_t)(tt + 1) * 64,
          true, tid, rA0, rB0, lq, K, acc);
    ktile(As1, Bs1, As0, Bs0,
          aTile + (size_t)(tt + 2) * 64, bTile + (size_t)(tt + 2) * 64,
          (tt + 2 < nT), tid, rA0, rB0, lq, K, acc);
  }

  float bj[4];
#pragma unroll
  for (int j = 0; j < 4; ++j)
    bj[j] = bias[nBase + wc * 64 + j * 16 + l15];

#pragma unroll
  for (int i = 0; i < 8; ++i) {
    const int rb = mBase + wr * 128 + i * 16 + lq * 4;
#pragma unroll
    for (int j = 0; j < 4; ++j) {
      const int cn = nBase + wc * 64 + j * 16 + l15;
#pragma unroll
      for (int r = 0; r < 4; ++r) {
        float c = acc[i][j][r] + bj[j];
        float v = GELU ? gelu_quant(c, ytA, ytS) : rintf(c * QS) * QINV;
        C[(size_t)(rb + r) * N + cn] = (OutT)v;
      }
    }
  }
}

// ======================= fused prep (verified r5-r8) =======================
__global__ __launch_bounds__(256)
void prep_kernel(const float* __restrict__ x, bf16_t* __restrict__ xb,
                 const float* __restrict__ w1, bf16_t* __restrict__ w1t,
                 const float* __restrict__ w2, bf16_t* __restrict__ w2t) {
  __shared__ float t[32][33];
  const int id = blockIdx.x;
  const int tid = threadIdx.x;
  if (id < 16384) {
    const int idx = id * 256 + tid;
    const float4 v = ((const float4*)x)[idx];
    bf16x4 o;
    o[0] = (bf16_t)v.x; o[1] = (bf16_t)v.y; o[2] = (bf16_t)v.z; o[3] = (bf16_t)v.w;
    ((bf16x4*)xb)[idx] = o;
  } else {
    const float* in; bf16_t* out; int R, C, bx, by;
    if (id < 20480) {
      const int id2 = id - 16384;
      in = w1; out = w1t; R = 1024; C = 4096;
      bx = id2 & 127; by = id2 >> 7;
    } else {
      const int id3 = id - 20480;
      in = w2; out = w2t; R = 4096; C = 1024;
      bx = id3 & 31; by = id3 >> 5;
    }
    const int c0 = bx * 32;
    const int r0 = by * 32;
    const int tx = tid & 31;
    const int ty = tid >> 5;
#pragma unroll
    for (int dy = 0; dy < 32; dy += 8)
      t[ty + dy][tx] = in[(size_t)(r0 + ty + dy) * C + c0 + tx];
    __syncthreads();
#pragma unroll
    for (int dy = 0; dy < 32; dy += 8)
      out[(size_t)(c0 + ty + dy) * R + r0 + tx] = (bf16_t)t[tx][ty + dy];
  }
}

extern "C" void kernel_launch(void* const* d_in, const int* in_sizes, int n_in,
                              void* d_out, int out_size, void* d_ws, size_t ws_size,
                              hipStream_t stream) {
  const float* x  = (const float*)d_in[0];   // [32,512,1024] = [16384][1024]
  const float* w1 = (const float*)d_in[1];   // [1024][4096]
  const float* b1 = (const float*)d_in[2];   // [4096]
  const float* w2 = (const float*)d_in[3];   // [4096][1024]
  const float* b2 = (const float*)d_in[4];   // [1024]
  float* out = (float*)d_out;                // [16384][1024]

  const int M = 16384, D = 1024, F = 4096;

  char* ws = (char*)d_ws;
  size_t off = 0;
  bf16_t* xb  = (bf16_t*)(ws + off); off += (size_t)M * D * 2;
  bf16_t* w1t = (bf16_t*)(ws + off); off += (size_t)D * F * 2;
  bf16_t* w2t = (bf16_t*)(ws + off); off += (size_t)F * D * 2;
  bf16_t* h   = (bf16_t*)(ws + off);

  prep_kernel<<<16384 + 4096 + 4096, 256, 0, stream>>>(x, xb, w1, w1t, w2, w2t);

  // GEMM1: verified round-0 config (128^2, no swizzle) -> h
  gemm128<true, bf16_t><<<dim3(F / 128, M / 128), 256, 0, stream>>>(xb, w1t, b1, h, M, F, D);
  // GEMM2: 256^2 8-phase minus sched_barrier (m141 A/B), no swizzle -> out
  gemm256<false, float><<<dim3(D / 256, M / 256), 512, 0, stream>>>(h, w2t, b2, out, M, D, F);
}